// Round 1
// 401.609 us; speedup vs baseline: 1.0126x; 1.0126x over previous
//
#include <hip/hip_runtime.h>
#include <hip/hip_bf16.h>
#include <math.h>

// Problem constants (from reference)
#define B_SZ 32
#define T_SZ 4096
#define DV   512   // DIM_VECT
#define DA   256   // DIM_ATTN
#define DK   512   // DIM_ATTN_BID (matrix feature dim)

typedef __attribute__((ext_vector_type(8))) __bf16 bf16x8;
typedef __attribute__((ext_vector_type(4))) __bf16 bf16x4;
typedef __attribute__((ext_vector_type(2))) __bf16 bf16x2;
typedef __attribute__((ext_vector_type(4))) float  f32x4;

// Lengths may arrive as int32 or int64. Valid lengths are in [1, 4096], so for
// int64 little-endian p[1]==0; for int32 p[1] is a real length >= 1.
__device__ inline int get_len(const int* __restrict__ p, int b) {
    return (p[1] == 0) ? p[2 * b] : p[b];
}

// ---------------------------------------------------------------------------
// Kernel 0 (fused setup): blocks 0..127 convert W_mat f32->bf16;
// blocks 128..159 compute t1[b,a] = vector[b,:]·W_vec[a,:].
// ---------------------------------------------------------------------------
__global__ void setup_kernel(const float* __restrict__ wmat, __bf16* __restrict__ wmat_bf,
                             const float* __restrict__ vector, const float* __restrict__ wvec,
                             float* __restrict__ t1) {
    int blk = blockIdx.x, tid = threadIdx.x;
    if (blk < 128) {
        int i = (blk * 256 + tid) * 4;
        float4 v = *(const float4*)(wmat + i);
        bf16x4 o;
        o[0] = (__bf16)v.x; o[1] = (__bf16)v.y; o[2] = (__bf16)v.z; o[3] = (__bf16)v.w;
        *(bf16x4*)(wmat_bf + i) = o;
        return;
    }
    int b = blk - 128;
    __shared__ float sv[DV];
    sv[tid]       = vector[b * DV + tid];
    sv[tid + 256] = vector[b * DV + tid + 256];
    __syncthreads();
    const float4* w  = (const float4*)(wvec + (size_t)tid * DV);
    const float4* s4 = (const float4*)sv;
    float acc = 0.f;
#pragma unroll 8
    for (int k = 0; k < DV / 4; k++) {
        float4 wv = w[k]; float4 xv = s4[k];
        acc += wv.x * xv.x + wv.y * xv.y + wv.z * xv.z + wv.w * xv.w;
    }
    t1[b * DA + tid] = acc;
}

// ---------------------------------------------------------------------------
// Kernel 1: fused logits + block-local online-softmax partials.
// GEMM: A staged f32->bf16 into a PERSISTENT [64][520] bf16 LDS tile (each
// k-slab written once into its own column range -> no double buffer needed,
// same one-barrier-per-k-step pipeline, tile survives the whole GEMM).
// B direct-to-register, prefetched; BK=64.
// Epilogue: per-block local max m_blk, s_blk, and partial
// P[d] = sum_t exp(l_t - m_blk)*M[t,d] computed FROM THE LDS TILE (bf16) —
// this removes the ~matrix-sized global re-read that previously missed L2.
// ---------------------------------------------------------------------------
#define TM   64
#define LDA2 520                 // 512 + 8 pad elems: row stride 1040 B ≡ 4 banks, 16B-aligned
#define NBLK (T_SZ / TM)         // 64 t-blocks per batch row

__global__ __launch_bounds__(256) void logits_kernel(
    const float* __restrict__ matrix, const __bf16* __restrict__ wmat,
    const float* __restrict__ t1, const float* __restrict__ wattn,
    const int* __restrict__ lens, float* __restrict__ logits,
    float* __restrict__ P, float* __restrict__ ms) {
    int b  = blockIdx.y;
    int blk = blockIdx.x;
    int t0 = blk * TM;
    int len = get_len(lens, b);
    if (t0 >= len) return;   // inactive blocks: combine kernel never reads their slots

    __shared__ __bf16 sA[TM][LDA2];      // 66.56 KB persistent tile
    __shared__ float s_t1[DA];
    __shared__ float s_wa[DA];
    __shared__ float s_logit[TM];
    __shared__ float sw[TM];

    int tid = threadIdx.x;
    s_t1[tid] = t1[b * DA + tid];
    s_wa[tid] = wattn[tid];
    if (tid < TM) s_logit[tid] = 0.f;

    int wave = tid >> 6, lane = tid & 63;
    int col  = lane & 15;            // t-row (A) / a-col (B) within 16x16 tile
    int koff = (lane >> 4) * 8;      // k sub-offset (bf16 elems)

    // staging assignment: 16 lanes per row, 4 floats (16B) per lane
    int srow = tid >> 4;             // 0..15 (rows srow, srow+16, +32, +48)
    int soff = (tid & 15) * 4;       // k index 0..60

    const float* Abase = matrix + ((size_t)b * T_SZ + t0) * DK;
    const __bf16* Bp[4];
#pragma unroll
    for (int nt = 0; nt < 4; nt++)
        Bp[nt] = wmat + (size_t)(wave * 64 + nt * 16 + col) * DK + koff;

    f32x4 acc[4][4];
    f32x4 zero = {0.f, 0.f, 0.f, 0.f};
#pragma unroll
    for (int i = 0; i < 4; i++)
#pragma unroll
        for (int j = 0; j < 4; j++) acc[i][j] = zero;

    // prologue: stage k-slab 0 into cols [0,64), prefetch B for step 0
#pragma unroll
    for (int r = 0; r < 4; r++) {
        float4 v = *(const float4*)(Abase + (size_t)(srow + r * 16) * DK + soff);
        bf16x4 o;
        o[0] = (__bf16)v.x; o[1] = (__bf16)v.y; o[2] = (__bf16)v.z; o[3] = (__bf16)v.w;
        *(bf16x4*)&sA[srow + r * 16][soff] = o;
    }
    uint4 pb[8];
#pragma unroll
    for (int s = 0; s < 2; s++)
#pragma unroll
        for (int nt = 0; nt < 4; nt++)
            pb[s * 4 + nt] = *(const uint4*)(Bp[nt] + s * 32);

    __syncthreads();

    for (int ks = 0; ks < 8; ks++) {
        int kb = ks * 64;
        float4 na[4];
        uint4  nb[8];
        if (ks < 7) {
            int k1 = kb + 64;
#pragma unroll
            for (int r = 0; r < 4; r++)
                na[r] = *(const float4*)(Abase + (size_t)(srow + r * 16) * DK + k1 + soff);
#pragma unroll
            for (int s = 0; s < 2; s++)
#pragma unroll
                for (int nt = 0; nt < 4; nt++)
                    nb[s * 4 + nt] = *(const uint4*)(Bp[nt] + k1 + s * 32);
        }
        bf16x8 af[2][4];
#pragma unroll
        for (int s = 0; s < 2; s++)
#pragma unroll
            for (int mt = 0; mt < 4; mt++)
                af[s][mt] = *(const bf16x8*)&sA[mt * 16 + col][kb + s * 32 + koff];
#pragma unroll
        for (int s = 0; s < 2; s++)
#pragma unroll
            for (int mt = 0; mt < 4; mt++)
#pragma unroll
                for (int nt = 0; nt < 4; nt++)
                    acc[mt][nt] = __builtin_amdgcn_mfma_f32_16x16x32_bf16(
                        af[s][mt], *(bf16x8*)&pb[s * 4 + nt], acc[mt][nt], 0, 0, 0);
        if (ks < 7) {
            int k1 = kb + 64;
#pragma unroll
            for (int r = 0; r < 4; r++) {
                bf16x4 o;
                o[0] = (__bf16)na[r].x; o[1] = (__bf16)na[r].y;
                o[2] = (__bf16)na[r].z; o[3] = (__bf16)na[r].w;
                *(bf16x4*)&sA[srow + r * 16][k1 + soff] = o;
            }
#pragma unroll
            for (int i = 0; i < 8; i++) pb[i] = nb[i];
        }
        __syncthreads();
    }

    // logits epilogue: v = W_attn[a]*relu(t1[a]+t2), reduce over wave's a-quarter.
    // C/D layout (verified): col = lane&15, row = (lane>>4)*4 + reg
    int rg = lane >> 4;
#pragma unroll
    for (int mt = 0; mt < 4; mt++) {
#pragma unroll
        for (int r = 0; r < 4; r++) {
            float v = 0.f;
#pragma unroll
            for (int nt = 0; nt < 4; nt++) {
                int a = wave * 64 + nt * 16 + col;
                float x = acc[mt][nt][r] + s_t1[a];
                v += s_wa[a] * fmaxf(x, 0.f);
            }
#pragma unroll
            for (int off = 1; off < 16; off <<= 1) v += __shfl_xor(v, off, 64);
            if (col == 0) atomicAdd(&s_logit[mt * 16 + rg * 4 + r], v);
        }
    }
    __syncthreads();

    // block-local online-softmax stats (wave 0 only: lane t holds logit t)
    if (tid < TM) {
        float l = s_logit[tid];
        bool valid = (t0 + tid) < len;
        float m = valid ? l : -1e30f;
#pragma unroll
        for (int off = 32; off; off >>= 1) m = fmaxf(m, __shfl_xor(m, off, 64));
        float w = valid ? __expf(l - m) : 0.f;
        sw[tid] = w;
        float s = w;
#pragma unroll
        for (int off = 32; off; off >>= 1) s += __shfl_xor(s, off, 64);
        if (tid == 0) {
            ms[(b * NBLK + blk) * 2]     = m;
            ms[(b * NBLK + blk) * 2 + 1] = s;
        }
        logits[(size_t)b * T_SZ + t0 + tid] = l;   // raw logit (masked later)
    }
    __syncthreads();

    // partial representation: P[d] = sum_t sw[t] * M[t,d], read from the
    // persistent LDS tile (bf16) — no global re-read. At fixed t the wave
    // reads 256 contiguous bytes (2-way bank alias = free).
    int d = 2 * tid;
    int nv = min(TM, len - t0);
    float p0 = 0.f, p1 = 0.f;
#pragma unroll 4
    for (int t = 0; t < nv; t++) {
        float w = sw[t];
        bf16x2 mv = *(const bf16x2*)&sA[t][d];
        p0 = fmaf(w, (float)mv[0], p0);
        p1 = fmaf(w, (float)mv[1], p1);
    }
    float* Pb = P + ((size_t)(b * NBLK + blk)) * DV;
    Pb[d]     = p0;
    Pb[d + 1] = p1;
}

// ---------------------------------------------------------------------------
// Kernel 2: combine partials (exact flash-style merge) + write rep + normalize
// attention row. One block per batch row, 1024 threads.
// ---------------------------------------------------------------------------
__global__ __launch_bounds__(1024) void combine_kernel(
    const int* __restrict__ lens, const float* __restrict__ P,
    const float* __restrict__ ms, float* __restrict__ rep,
    float* __restrict__ attn) {
    int b = blockIdx.x, tid = threadIdx.x;
    int len = get_len(lens, b);
    int nblk = (len + TM - 1) / TM;

    __shared__ float sm[NBLK];      // local maxes
    __shared__ float sscale[NBLK];  // exp(m_blk - m)
    __shared__ float s_gm, s_gS;

    if (tid < NBLK) {
        if (tid < nblk) {
            sm[tid]     = ms[(b * NBLK + tid) * 2];
            sscale[tid] = ms[(b * NBLK + tid) * 2 + 1];   // temp: s_blk
        } else {
            sm[tid] = -1e30f; sscale[tid] = 0.f;
        }
    }
    __syncthreads();
    if (tid < NBLK) {   // single wave... NBLK=64 -> exactly wave 0
        float m = sm[tid];
#pragma unroll
        for (int off = 32; off; off >>= 1) m = fmaxf(m, __shfl_xor(m, off, 64));
        float sc = (tid < nblk) ? __expf(sm[tid] - m) : 0.f;
        float S = sc * sscale[tid];
#pragma unroll
        for (int off = 32; off; off >>= 1) S += __shfl_xor(S, off, 64);
        sscale[tid] = sc;
        if (tid == 0) { s_gm = m; s_gS = S; }
    }
    __syncthreads();
    float m = s_gm;
    float invS = 1.f / s_gS;

    // rep[b,d] = invS * sum_blk sscale[blk] * P[b,blk,d]
    if (tid < DV) {
        float acc = 0.f;
        const float* Pb = P + (size_t)b * NBLK * DV + tid;
        for (int blk = 0; blk < nblk; blk++)
            acc += sscale[blk] * Pb[(size_t)blk * DV];
        rep[b * DV + tid] = acc * invS;
    }

    // normalize attention row
    float* row = attn + (size_t)b * T_SZ;
#pragma unroll
    for (int i = 0; i < T_SZ / 1024; i++) {
        int t = tid + i * 1024;
        float l = row[t];
        row[t] = (t < len) ? __expf(l - m) * invS : 0.f;
    }
}

// ---------------------------------------------------------------------------
extern "C" void kernel_launch(void* const* d_in, const int* in_sizes, int n_in,
                              void* d_out, int out_size, void* d_ws, size_t ws_size,
                              hipStream_t stream) {
    const float* vector = (const float*)d_in[0];
    const float* matrix = (const float*)d_in[1];
    const int*   lens   = (const int*)d_in[2];
    const float* wvec   = (const float*)d_in[3];
    const float* wmat   = (const float*)d_in[4];
    const float* wattn  = (const float*)d_in[5];

    float* rep  = (float*)d_out;            // [32, 512]
    float* attn = rep + B_SZ * DV;          // [32, 4096] raw logits -> normalized

    char* ws = (char*)d_ws;
    float*  t1      = (float*)ws;                        // 32 KB
    __bf16* wmat_bf = (__bf16*)(ws + 32768);             // 256 KB
    float*  P       = (float*)(ws + 32768 + 262144);     // 32*64*512 f32 = 4 MB
    float*  ms      = (float*)(ws + 32768 + 262144 + 4194304);  // 32*64*2 f32 = 16 KB

    setup_kernel<<<dim3(160), 256, 0, stream>>>(wmat, wmat_bf, vector, wvec, t1);
    logits_kernel<<<dim3(NBLK, B_SZ), 256, 0, stream>>>(matrix, wmat_bf, t1, wattn,
                                                        lens, attn, P, ms);
    combine_kernel<<<dim3(B_SZ), 1024, 0, stream>>>(lens, P, ms, rep, attn);
}

// Round 3
// 398.875 us; speedup vs baseline: 1.0195x; 1.0069x over previous
//
#include <hip/hip_runtime.h>
#include <hip/hip_bf16.h>
#include <math.h>

// Problem constants (from reference)
#define B_SZ 32
#define T_SZ 4096
#define DV   512   // DIM_VECT
#define DA   256   // DIM_ATTN
#define DK   512   // DIM_ATTN_BID (matrix feature dim)

typedef __attribute__((ext_vector_type(8))) __bf16 bf16x8;
typedef __attribute__((ext_vector_type(4))) __bf16 bf16x4;
typedef __attribute__((ext_vector_type(2))) __bf16 bf16x2;
typedef __attribute__((ext_vector_type(4))) float  f32x4;

// Lengths may arrive as int32 or int64. Valid lengths are in [1, 4096], so for
// int64 little-endian p[1]==0; for int32 p[1] is a real length >= 1.
__device__ inline int get_len(const int* __restrict__ p, int b) {
    return (p[1] == 0) ? p[2 * b] : p[b];
}

// ---------------------------------------------------------------------------
// Kernel 0 (fused setup): blocks 0..127 convert W_mat f32->bf16;
// blocks 128..159 compute t1[b,a] = vector[b,:]·W_vec[a,:].
// ---------------------------------------------------------------------------
__global__ void setup_kernel(const float* __restrict__ wmat, __bf16* __restrict__ wmat_bf,
                             const float* __restrict__ vector, const float* __restrict__ wvec,
                             float* __restrict__ t1) {
    int blk = blockIdx.x, tid = threadIdx.x;
    if (blk < 128) {
        int i = (blk * 256 + tid) * 4;
        float4 v = *(const float4*)(wmat + i);
        bf16x4 o;
        o[0] = (__bf16)v.x; o[1] = (__bf16)v.y; o[2] = (__bf16)v.z; o[3] = (__bf16)v.w;
        *(bf16x4*)(wmat_bf + i) = o;
        return;
    }
    int b = blk - 128;
    __shared__ float sv[DV];
    sv[tid]       = vector[b * DV + tid];
    sv[tid + 256] = vector[b * DV + tid + 256];
    __syncthreads();
    const float4* w  = (const float4*)(wvec + (size_t)tid * DV);
    const float4* s4 = (const float4*)sv;
    float acc = 0.f;
#pragma unroll 8
    for (int k = 0; k < DV / 4; k++) {
        float4 wv = w[k]; float4 xv = s4[k];
        acc += wv.x * xv.x + wv.y * xv.y + wv.z * xv.z + wv.w * xv.w;
    }
    t1[b * DA + tid] = acc;
}

// ---------------------------------------------------------------------------
// Kernel 1: fused logits + block-local online-softmax partials.
// GEMM: A staged f32->bf16 into a PERSISTENT [64][520] bf16 LDS tile.
// Depth-2 register prefetch for the A (HBM) stream — A slab k+2 is issued at
// step k, written to LDS at end of step k+1 (doubles HBM bytes in flight).
// B (L2-resident) at prefetch distance 1. Loop body hand-unrolled 2x so all
// register-pipeline indices are literals (no runtime-indexed reg arrays).
// Epilogue: block-local softmax stats + P[d] partial from the LDS tile.
// ---------------------------------------------------------------------------
#define TM   64
#define LDA2 520                 // 512 + 8 pad elems: row stride 1040 B ≡ 4 banks, 16B-aligned
#define NBLK (T_SZ / TM)         // 64 t-blocks per batch row

__global__ __launch_bounds__(256) void logits_kernel(
    const float* __restrict__ matrix, const __bf16* __restrict__ wmat,
    const float* __restrict__ t1, const float* __restrict__ wattn,
    const int* __restrict__ lens, float* __restrict__ logits,
    float* __restrict__ P, float* __restrict__ ms) {
    int b  = blockIdx.y;
    int blk = blockIdx.x;
    int t0 = blk * TM;
    int len = get_len(lens, b);
    if (t0 >= len) return;   // inactive blocks: combine kernel never reads their slots

    __shared__ __bf16 sA[TM][LDA2];      // 66.56 KB persistent tile
    __shared__ float s_t1[DA];
    __shared__ float s_wa[DA];
    __shared__ float s_logit[TM];
    __shared__ float sw[TM];

    int tid = threadIdx.x;
    s_t1[tid] = t1[b * DA + tid];
    s_wa[tid] = wattn[tid];
    if (tid < TM) s_logit[tid] = 0.f;

    int wave = tid >> 6, lane = tid & 63;
    int col  = lane & 15;            // t-row (A) / a-col (B) within 16x16 tile
    int koff = (lane >> 4) * 8;      // k sub-offset (bf16 elems)

    // staging assignment: 16 lanes per row, 4 floats (16B) per lane
    int srow = tid >> 4;             // 0..15 (rows srow, srow+16, +32, +48)
    int soff = (tid & 15) * 4;       // k index 0..60

    const float* Abase = matrix + ((size_t)b * T_SZ + t0) * DK;
    const __bf16* Bp[4];
#pragma unroll
    for (int nt = 0; nt < 4; nt++)
        Bp[nt] = wmat + (size_t)(wave * 64 + nt * 16 + col) * DK + koff;

    f32x4 acc[4][4];
    f32x4 zero = {0.f, 0.f, 0.f, 0.f};
#pragma unroll
    for (int i = 0; i < 4; i++)
#pragma unroll
        for (int j = 0; j < 4; j++) acc[i][j] = zero;

    float4 arA[4], arB[4];   // A-slab register pipeline (two named banks)
    uint4  brA[8], brB[8];   // B-slab register pipeline

    // ---- prologue: issue A slab0 (->arA) + slab1 (->arB) and B slab0 (->brA);
    //      convert+write slab0 to LDS cols [0,64)
#pragma unroll
    for (int r = 0; r < 4; r++)
        arA[r] = *(const float4*)(Abase + (size_t)(srow + r * 16) * DK + soff);
#pragma unroll
    for (int r = 0; r < 4; r++)
        arB[r] = *(const float4*)(Abase + (size_t)(srow + r * 16) * DK + 64 + soff);
#pragma unroll
    for (int s = 0; s < 2; s++)
#pragma unroll
        for (int nt = 0; nt < 4; nt++)
            brA[s * 4 + nt] = *(const uint4*)(Bp[nt] + s * 32);

#pragma unroll
    for (int r = 0; r < 4; r++) {
        float4 v = arA[r];
        bf16x4 o;
        o[0] = (__bf16)v.x; o[1] = (__bf16)v.y; o[2] = (__bf16)v.z; o[3] = (__bf16)v.w;
        *(bf16x4*)&sA[srow + r * 16][soff] = o;
    }
    __syncthreads();

    // ---- one pipeline step: consume slab ks (LDS + brCUR), issue A ks+2
    //      (->arCUR), issue B ks+1 (->brNXT), write A ks+1 (arNXT) to LDS.
#define K_STEP(ks, arCUR, arNXT, brCUR, brNXT)                                        \
    {                                                                                 \
        const int kb = (ks) * 64;                                                     \
        if ((ks) < 6) {                                                               \
            _Pragma("unroll")                                                         \
            for (int r = 0; r < 4; r++)                                               \
                arCUR[r] = *(const float4*)(Abase + (size_t)(srow + r * 16) * DK      \
                                            + kb + 128 + soff);                       \
        }                                                                             \
        if ((ks) < 7) {                                                               \
            _Pragma("unroll")                                                         \
            for (int s = 0; s < 2; s++)                                               \
                _Pragma("unroll")                                                     \
                for (int nt = 0; nt < 4; nt++)                                        \
                    brNXT[s * 4 + nt] = *(const uint4*)(Bp[nt] + kb + 64 + s * 32);   \
        }                                                                             \
        bf16x8 af[2][4];                                                              \
        _Pragma("unroll")                                                             \
        for (int s = 0; s < 2; s++)                                                   \
            _Pragma("unroll")                                                         \
            for (int mt = 0; mt < 4; mt++)                                            \
                af[s][mt] = *(const bf16x8*)&sA[mt * 16 + col][kb + s * 32 + koff];   \
        _Pragma("unroll")                                                             \
        for (int s = 0; s < 2; s++)                                                   \
            _Pragma("unroll")                                                         \
            for (int mt = 0; mt < 4; mt++)                                            \
                _Pragma("unroll")                                                     \
                for (int nt = 0; nt < 4; nt++)                                        \
                    acc[mt][nt] = __builtin_amdgcn_mfma_f32_16x16x32_bf16(            \
                        af[s][mt], *(bf16x8*)&brCUR[s * 4 + nt], acc[mt][nt], 0, 0, 0); \
        if ((ks) < 7) {                                                               \
            _Pragma("unroll")                                                         \
            for (int r = 0; r < 4; r++) {                                             \
                float4 v = arNXT[r];                                                  \
                bf16x4 o;                                                             \
                o[0] = (__bf16)v.x; o[1] = (__bf16)v.y;                               \
                o[2] = (__bf16)v.z; o[3] = (__bf16)v.w;                               \
                *(bf16x4*)&sA[srow + r * 16][kb + 64 + soff] = o;                     \
            }                                                                         \
        }                                                                             \
        __syncthreads();                                                              \
    }

    K_STEP(0, arA, arB, brA, brB)
    K_STEP(1, arB, arA, brB, brA)
    K_STEP(2, arA, arB, brA, brB)
    K_STEP(3, arB, arA, brB, brA)
    K_STEP(4, arA, arB, brA, brB)
    K_STEP(5, arB, arA, brB, brA)
    K_STEP(6, arA, arB, brA, brB)
    K_STEP(7, arB, arA, brB, brA)
#undef K_STEP

    // logits epilogue: v = W_attn[a]*relu(t1[a]+t2), reduce over wave's a-quarter.
    // C/D layout (verified): col = lane&15, row = (lane>>4)*4 + reg
    int rg = lane >> 4;
#pragma unroll
    for (int mt = 0; mt < 4; mt++) {
#pragma unroll
        for (int r = 0; r < 4; r++) {
            float v = 0.f;
#pragma unroll
            for (int nt = 0; nt < 4; nt++) {
                int a = wave * 64 + nt * 16 + col;
                float x = acc[mt][nt][r] + s_t1[a];
                v += s_wa[a] * fmaxf(x, 0.f);
            }
#pragma unroll
            for (int off = 1; off < 16; off <<= 1) v += __shfl_xor(v, off, 64);
            if (col == 0) atomicAdd(&s_logit[mt * 16 + rg * 4 + r], v);
        }
    }
    __syncthreads();

    // block-local online-softmax stats (wave 0 only: lane t holds logit t)
    if (tid < TM) {
        float l = s_logit[tid];
        bool valid = (t0 + tid) < len;
        float m = valid ? l : -1e30f;
#pragma unroll
        for (int off = 32; off; off >>= 1) m = fmaxf(m, __shfl_xor(m, off, 64));
        float w = valid ? __expf(l - m) : 0.f;
        sw[tid] = w;
        float s = w;
#pragma unroll
        for (int off = 32; off; off >>= 1) s += __shfl_xor(s, off, 64);
        if (tid == 0) {
            ms[(b * NBLK + blk) * 2]     = m;
            ms[(b * NBLK + blk) * 2 + 1] = s;
        }
        logits[(size_t)b * T_SZ + t0 + tid] = l;   // raw logit (masked later)
    }
    __syncthreads();

    // partial representation: P[d] = sum_t sw[t] * M[t,d], read from the
    // persistent LDS tile (bf16) — no global re-read. At fixed t the wave
    // reads 256 contiguous bytes (2-way bank alias = free).
    int d = 2 * tid;
    int nv = min(TM, len - t0);
    float p0 = 0.f, p1 = 0.f;
#pragma unroll 4
    for (int t = 0; t < nv; t++) {
        float w = sw[t];
        bf16x2 mv = *(const bf16x2*)&sA[t][d];
        p0 = fmaf(w, (float)mv[0], p0);
        p1 = fmaf(w, (float)mv[1], p1);
    }
    float* Pb = P + ((size_t)(b * NBLK + blk)) * DV;
    Pb[d]     = p0;
    Pb[d + 1] = p1;
}

// ---------------------------------------------------------------------------
// Kernel 2: combine partials (exact flash-style merge) + write rep + normalize
// attention row. One block per batch row, 1024 threads.
// ---------------------------------------------------------------------------
__global__ __launch_bounds__(1024) void combine_kernel(
    const int* __restrict__ lens, const float* __restrict__ P,
    const float* __restrict__ ms, float* __restrict__ rep,
    float* __restrict__ attn) {
    int b = blockIdx.x, tid = threadIdx.x;
    int len = get_len(lens, b);
    int nblk = (len + TM - 1) / TM;

    __shared__ float sm[NBLK];      // local maxes
    __shared__ float sscale[NBLK];  // exp(m_blk - m)
    __shared__ float s_gm, s_gS;

    if (tid < NBLK) {
        if (tid < nblk) {
            sm[tid]     = ms[(b * NBLK + tid) * 2];
            sscale[tid] = ms[(b * NBLK + tid) * 2 + 1];   // temp: s_blk
        } else {
            sm[tid] = -1e30f; sscale[tid] = 0.f;
        }
    }
    __syncthreads();
    if (tid < NBLK) {   // single wave... NBLK=64 -> exactly wave 0
        float m = sm[tid];
#pragma unroll
        for (int off = 32; off; off >>= 1) m = fmaxf(m, __shfl_xor(m, off, 64));
        float sc = (tid < nblk) ? __expf(sm[tid] - m) : 0.f;
        float S = sc * sscale[tid];
#pragma unroll
        for (int off = 32; off; off >>= 1) S += __shfl_xor(S, off, 64);
        sscale[tid] = sc;
        if (tid == 0) { s_gm = m; s_gS = S; }
    }
    __syncthreads();
    float m = s_gm;
    float invS = 1.f / s_gS;

    // rep[b,d] = invS * sum_blk sscale[blk] * P[b,blk,d]
    if (tid < DV) {
        float acc = 0.f;
        const float* Pb = P + (size_t)b * NBLK * DV + tid;
        for (int blk = 0; blk < nblk; blk++)
            acc += sscale[blk] * Pb[(size_t)blk * DV];
        rep[b * DV + tid] = acc * invS;
    }

    // normalize attention row
    float* row = attn + (size_t)b * T_SZ;
#pragma unroll
    for (int i = 0; i < T_SZ / 1024; i++) {
        int t = tid + i * 1024;
        float l = row[t];
        row[t] = (t < len) ? __expf(l - m) * invS : 0.f;
    }
}

// ---------------------------------------------------------------------------
extern "C" void kernel_launch(void* const* d_in, const int* in_sizes, int n_in,
                              void* d_out, int out_size, void* d_ws, size_t ws_size,
                              hipStream_t stream) {
    const float* vector = (const float*)d_in[0];
    const float* matrix = (const float*)d_in[1];
    const int*   lens   = (const int*)d_in[2];
    const float* wvec   = (const float*)d_in[3];
    const float* wmat   = (const float*)d_in[4];
    const float* wattn  = (const float*)d_in[5];

    float* rep  = (float*)d_out;            // [32, 512]
    float* attn = rep + B_SZ * DV;          // [32, 4096] raw logits -> normalized

    char* ws = (char*)d_ws;
    float*  t1      = (float*)ws;                        // 32 KB
    __bf16* wmat_bf = (__bf16*)(ws + 32768);             // 256 KB
    float*  P       = (float*)(ws + 32768 + 262144);     // 32*64*512 f32 = 4 MB
    float*  ms      = (float*)(ws + 32768 + 262144 + 4194304);  // 32*64*2 f32 = 16 KB

    setup_kernel<<<dim3(160), 256, 0, stream>>>(wmat, wmat_bf, vector, wvec, t1);
    logits_kernel<<<dim3(NBLK, B_SZ), 256, 0, stream>>>(matrix, wmat_bf, t1, wattn,
                                                        lens, attn, P, ms);
    combine_kernel<<<dim3(B_SZ), 1024, 0, stream>>>(lens, P, ms, rep, attn);
}

// Round 4
// 398.035 us; speedup vs baseline: 1.0217x; 1.0021x over previous
//
#include <hip/hip_runtime.h>
#include <hip/hip_bf16.h>
#include <math.h>

// Problem constants (from reference)
#define B_SZ 32
#define T_SZ 4096
#define DV   512   // DIM_VECT
#define DA   256   // DIM_ATTN
#define DK   512   // DIM_ATTN_BID (matrix feature dim)

typedef __attribute__((ext_vector_type(8))) __bf16 bf16x8;
typedef __attribute__((ext_vector_type(4))) __bf16 bf16x4;
typedef __attribute__((ext_vector_type(2))) __bf16 bf16x2;
typedef __attribute__((ext_vector_type(4))) float  f32x4;

// Lengths may arrive as int32 or int64. Valid lengths are in [1, 4096], so for
// int64 little-endian p[1]==0; for int32 p[1] is a real length >= 1.
__device__ inline int get_len(const int* __restrict__ p, int b) {
    return (p[1] == 0) ? p[2 * b] : p[b];
}

// Counted-wait barrier: retire our ds_writes (visible CU-locally), then raw
// s_barrier. Unlike __syncthreads(), does NOT drain vmcnt — prefetched global
// loads stay in flight across the barrier (T4, m218).
#define BAR_LDS()                                             \
    do {                                                      \
        asm volatile("s_waitcnt lgkmcnt(0)" ::: "memory");    \
        __builtin_amdgcn_s_barrier();                         \
    } while (0)

// ---------------------------------------------------------------------------
// Kernel 0 (fused setup): blocks 0..127 convert W_mat f32->bf16;
// blocks 128..159 compute t1[b,a] = vector[b,:]·W_vec[a,:].
// ---------------------------------------------------------------------------
__global__ void setup_kernel(const float* __restrict__ wmat, __bf16* __restrict__ wmat_bf,
                             const float* __restrict__ vector, const float* __restrict__ wvec,
                             float* __restrict__ t1) {
    int blk = blockIdx.x, tid = threadIdx.x;
    if (blk < 128) {
        int i = (blk * 256 + tid) * 4;
        float4 v = *(const float4*)(wmat + i);
        bf16x4 o;
        o[0] = (__bf16)v.x; o[1] = (__bf16)v.y; o[2] = (__bf16)v.z; o[3] = (__bf16)v.w;
        *(bf16x4*)(wmat_bf + i) = o;
        return;
    }
    int b = blk - 128;
    __shared__ float sv[DV];
    sv[tid]       = vector[b * DV + tid];
    sv[tid + 256] = vector[b * DV + tid + 256];
    __syncthreads();
    const float4* w  = (const float4*)(wvec + (size_t)tid * DV);
    const float4* s4 = (const float4*)sv;
    float acc = 0.f;
#pragma unroll 8
    for (int k = 0; k < DV / 4; k++) {
        float4 wv = w[k]; float4 xv = s4[k];
        acc += wv.x * xv.x + wv.y * xv.y + wv.z * xv.z + wv.w * xv.w;
    }
    t1[b * DA + tid] = acc;
}

// ---------------------------------------------------------------------------
// Kernel 1: fused logits + block-local online-softmax partials.
// GEMM: A staged f32->bf16 into a PERSISTENT [64][520] bf16 LDS tile.
// Depth-2 register prefetch for the A (HBM) stream; B (L2) at distance 1.
// NEW: k-loop barriers are lgkmcnt(0)+raw s_barrier (no vmcnt drain), so the
// prefetched global loads genuinely stay in flight across k-steps — the
// previous __syncthreads() was draining vmcnt(0) every step, collapsing the
// pipeline to depth 1 (this was why round-3's prefetch gained only ~3 µs).
// Epilogue: block-local softmax stats + P[d] partial from the LDS tile.
// ---------------------------------------------------------------------------
#define TM   64
#define LDA2 520                 // 512 + 8 pad elems: row stride 1040 B ≡ 4 banks, 16B-aligned
#define NBLK (T_SZ / TM)         // 64 t-blocks per batch row

__global__ __launch_bounds__(256) void logits_kernel(
    const float* __restrict__ matrix, const __bf16* __restrict__ wmat,
    const float* __restrict__ t1, const float* __restrict__ wattn,
    const int* __restrict__ lens, float* __restrict__ logits,
    float* __restrict__ P, float* __restrict__ ms) {
    int b  = blockIdx.y;
    int blk = blockIdx.x;
    int t0 = blk * TM;
    int len = get_len(lens, b);
    if (t0 >= len) return;   // inactive blocks: combine kernel never reads their slots

    __shared__ __bf16 sA[TM][LDA2];      // 66.56 KB persistent tile
    __shared__ float s_t1[DA];
    __shared__ float s_wa[DA];
    __shared__ float s_logit[TM];
    __shared__ float sw[TM];

    int tid = threadIdx.x;
    s_t1[tid] = t1[b * DA + tid];
    s_wa[tid] = wattn[tid];
    if (tid < TM) s_logit[tid] = 0.f;

    int wave = tid >> 6, lane = tid & 63;
    int col  = lane & 15;            // t-row (A) / a-col (B) within 16x16 tile
    int koff = (lane >> 4) * 8;      // k sub-offset (bf16 elems)

    // staging assignment: 16 lanes per row, 4 floats (16B) per lane
    int srow = tid >> 4;             // 0..15 (rows srow, srow+16, +32, +48)
    int soff = (tid & 15) * 4;       // k index 0..60

    const float* Abase = matrix + ((size_t)b * T_SZ + t0) * DK;
    const __bf16* Bp[4];
#pragma unroll
    for (int nt = 0; nt < 4; nt++)
        Bp[nt] = wmat + (size_t)(wave * 64 + nt * 16 + col) * DK + koff;

    f32x4 acc[4][4];
    f32x4 zero = {0.f, 0.f, 0.f, 0.f};
#pragma unroll
    for (int i = 0; i < 4; i++)
#pragma unroll
        for (int j = 0; j < 4; j++) acc[i][j] = zero;

    float4 arA[4], arB[4];   // A-slab register pipeline (two named banks)
    uint4  brA[8], brB[8];   // B-slab register pipeline

    // ---- prologue: issue A slab0 (->arA) + slab1 (->arB) and B slab0 (->brA);
    //      convert+write slab0 to LDS cols [0,64)
#pragma unroll
    for (int r = 0; r < 4; r++)
        arA[r] = *(const float4*)(Abase + (size_t)(srow + r * 16) * DK + soff);
#pragma unroll
    for (int r = 0; r < 4; r++)
        arB[r] = *(const float4*)(Abase + (size_t)(srow + r * 16) * DK + 64 + soff);
#pragma unroll
    for (int s = 0; s < 2; s++)
#pragma unroll
        for (int nt = 0; nt < 4; nt++)
            brA[s * 4 + nt] = *(const uint4*)(Bp[nt] + s * 32);

#pragma unroll
    for (int r = 0; r < 4; r++) {
        float4 v = arA[r];
        bf16x4 o;
        o[0] = (__bf16)v.x; o[1] = (__bf16)v.y; o[2] = (__bf16)v.z; o[3] = (__bf16)v.w;
        *(bf16x4*)&sA[srow + r * 16][soff] = o;
    }
    BAR_LDS();   // arB/brA stay in flight into step 0

    // ---- one pipeline step: consume slab ks (LDS + brCUR), issue A ks+2
    //      (->arCUR), issue B ks+1 (->brNXT), write A ks+1 (arNXT) to LDS.
#define K_STEP(ks, arCUR, arNXT, brCUR, brNXT)                                        \
    {                                                                                 \
        const int kb = (ks) * 64;                                                     \
        if ((ks) < 6) {                                                               \
            _Pragma("unroll")                                                         \
            for (int r = 0; r < 4; r++)                                               \
                arCUR[r] = *(const float4*)(Abase + (size_t)(srow + r * 16) * DK      \
                                            + kb + 128 + soff);                       \
        }                                                                             \
        if ((ks) < 7) {                                                               \
            _Pragma("unroll")                                                         \
            for (int s = 0; s < 2; s++)                                               \
                _Pragma("unroll")                                                     \
                for (int nt = 0; nt < 4; nt++)                                        \
                    brNXT[s * 4 + nt] = *(const uint4*)(Bp[nt] + kb + 64 + s * 32);   \
        }                                                                             \
        bf16x8 af[2][4];                                                              \
        _Pragma("unroll")                                                             \
        for (int s = 0; s < 2; s++)                                                   \
            _Pragma("unroll")                                                         \
            for (int mt = 0; mt < 4; mt++)                                            \
                af[s][mt] = *(const bf16x8*)&sA[mt * 16 + col][kb + s * 32 + koff];   \
        _Pragma("unroll")                                                             \
        for (int s = 0; s < 2; s++)                                                   \
            _Pragma("unroll")                                                         \
            for (int mt = 0; mt < 4; mt++)                                            \
                _Pragma("unroll")                                                     \
                for (int nt = 0; nt < 4; nt++)                                        \
                    acc[mt][nt] = __builtin_amdgcn_mfma_f32_16x16x32_bf16(            \
                        af[s][mt], *(bf16x8*)&brCUR[s * 4 + nt], acc[mt][nt], 0, 0, 0); \
        if ((ks) < 7) {                                                               \
            _Pragma("unroll")                                                         \
            for (int r = 0; r < 4; r++) {                                             \
                float4 v = arNXT[r];                                                  \
                bf16x4 o;                                                             \
                o[0] = (__bf16)v.x; o[1] = (__bf16)v.y;                               \
                o[2] = (__bf16)v.z; o[3] = (__bf16)v.w;                               \
                *(bf16x4*)&sA[srow + r * 16][kb + 64 + soff] = o;                     \
            }                                                                         \
        }                                                                             \
        BAR_LDS();                                                                    \
    }

    K_STEP(0, arA, arB, brA, brB)
    K_STEP(1, arB, arA, brB, brA)
    K_STEP(2, arA, arB, brA, brB)
    K_STEP(3, arB, arA, brB, brA)
    K_STEP(4, arA, arB, brA, brB)
    K_STEP(5, arB, arA, brB, brA)
    K_STEP(6, arA, arB, brA, brB)
    K_STEP(7, arB, arA, brB, brA)
#undef K_STEP

    // logits epilogue: v = W_attn[a]*relu(t1[a]+t2), reduce over wave's a-quarter.
    // C/D layout (verified): col = lane&15, row = (lane>>4)*4 + reg
    int rg = lane >> 4;
#pragma unroll
    for (int mt = 0; mt < 4; mt++) {
#pragma unroll
        for (int r = 0; r < 4; r++) {
            float v = 0.f;
#pragma unroll
            for (int nt = 0; nt < 4; nt++) {
                int a = wave * 64 + nt * 16 + col;
                float x = acc[mt][nt][r] + s_t1[a];
                v += s_wa[a] * fmaxf(x, 0.f);
            }
#pragma unroll
            for (int off = 1; off < 16; off <<= 1) v += __shfl_xor(v, off, 64);
            if (col == 0) atomicAdd(&s_logit[mt * 16 + rg * 4 + r], v);
        }
    }
    __syncthreads();

    // block-local online-softmax stats (wave 0 only: lane t holds logit t)
    if (tid < TM) {
        float l = s_logit[tid];
        bool valid = (t0 + tid) < len;
        float m = valid ? l : -1e30f;
#pragma unroll
        for (int off = 32; off; off >>= 1) m = fmaxf(m, __shfl_xor(m, off, 64));
        float w = valid ? __expf(l - m) : 0.f;
        sw[tid] = w;
        float s = w;
#pragma unroll
        for (int off = 32; off; off >>= 1) s += __shfl_xor(s, off, 64);
        if (tid == 0) {
            ms[(b * NBLK + blk) * 2]     = m;
            ms[(b * NBLK + blk) * 2 + 1] = s;
        }
        logits[(size_t)b * T_SZ + t0 + tid] = l;   // raw logit (masked later)
    }
    __syncthreads();

    // partial representation: P[d] = sum_t sw[t] * M[t,d], read from the
    // persistent LDS tile (bf16) — no global re-read. At fixed t the wave
    // reads 256 contiguous bytes (2-way bank alias = free).
    int d = 2 * tid;
    int nv = min(TM, len - t0);
    float p0 = 0.f, p1 = 0.f;
#pragma unroll 4
    for (int t = 0; t < nv; t++) {
        float w = sw[t];
        bf16x2 mv = *(const bf16x2*)&sA[t][d];
        p0 = fmaf(w, (float)mv[0], p0);
        p1 = fmaf(w, (float)mv[1], p1);
    }
    float* Pb = P + ((size_t)(b * NBLK + blk)) * DV;
    Pb[d]     = p0;
    Pb[d + 1] = p1;
}

// ---------------------------------------------------------------------------
// Kernel 2: combine partials (exact flash-style merge) + write rep + normalize
// attention row. One block per batch row, 1024 threads.
// ---------------------------------------------------------------------------
__global__ __launch_bounds__(1024) void combine_kernel(
    const int* __restrict__ lens, const float* __restrict__ P,
    const float* __restrict__ ms, float* __restrict__ rep,
    float* __restrict__ attn) {
    int b = blockIdx.x, tid = threadIdx.x;
    int len = get_len(lens, b);
    int nblk = (len + TM - 1) / TM;

    __shared__ float sm[NBLK];      // local maxes
    __shared__ float sscale[NBLK];  // exp(m_blk - m)
    __shared__ float s_gm, s_gS;

    if (tid < NBLK) {
        if (tid < nblk) {
            sm[tid]     = ms[(b * NBLK + tid) * 2];
            sscale[tid] = ms[(b * NBLK + tid) * 2 + 1];   // temp: s_blk
        } else {
            sm[tid] = -1e30f; sscale[tid] = 0.f;
        }
    }
    __syncthreads();
    if (tid < NBLK) {   // single wave... NBLK=64 -> exactly wave 0
        float m = sm[tid];
#pragma unroll
        for (int off = 32; off; off >>= 1) m = fmaxf(m, __shfl_xor(m, off, 64));
        float sc = (tid < nblk) ? __expf(sm[tid] - m) : 0.f;
        float S = sc * sscale[tid];
#pragma unroll
        for (int off = 32; off; off >>= 1) S += __shfl_xor(S, off, 64);
        sscale[tid] = sc;
        if (tid == 0) { s_gm = m; s_gS = S; }
    }
    __syncthreads();
    float m = s_gm;
    float invS = 1.f / s_gS;

    // rep[b,d] = invS * sum_blk sscale[blk] * P[b,blk,d]
    if (tid < DV) {
        float acc = 0.f;
        const float* Pb = P + (size_t)b * NBLK * DV + tid;
        for (int blk = 0; blk < nblk; blk++)
            acc += sscale[blk] * Pb[(size_t)blk * DV];
        rep[b * DV + tid] = acc * invS;
    }

    // normalize attention row
    float* row = attn + (size_t)b * T_SZ;
#pragma unroll
    for (int i = 0; i < T_SZ / 1024; i++) {
        int t = tid + i * 1024;
        float l = row[t];
        row[t] = (t < len) ? __expf(l - m) * invS : 0.f;
    }
}

// ---------------------------------------------------------------------------
extern "C" void kernel_launch(void* const* d_in, const int* in_sizes, int n_in,
                              void* d_out, int out_size, void* d_ws, size_t ws_size,
                              hipStream_t stream) {
    const float* vector = (const float*)d_in[0];
    const float* matrix = (const float*)d_in[1];
    const int*   lens   = (const int*)d_in[2];
    const float* wvec   = (const float*)d_in[3];
    const float* wmat   = (const float*)d_in[4];
    const float* wattn  = (const float*)d_in[5];

    float* rep  = (float*)d_out;            // [32, 512]
    float* attn = rep + B_SZ * DV;          // [32, 4096] raw logits -> normalized

    char* ws = (char*)d_ws;
    float*  t1      = (float*)ws;                        // 32 KB
    __bf16* wmat_bf = (__bf16*)(ws + 32768);             // 256 KB
    float*  P       = (float*)(ws + 32768 + 262144);     // 32*64*512 f32 = 4 MB
    float*  ms      = (float*)(ws + 32768 + 262144 + 4194304);  // 32*64*2 f32 = 16 KB

    setup_kernel<<<dim3(160), 256, 0, stream>>>(wmat, wmat_bf, vector, wvec, t1);
    logits_kernel<<<dim3(NBLK, B_SZ), 256, 0, stream>>>(matrix, wmat_bf, t1, wattn,
                                                        lens, attn, P, ms);
    combine_kernel<<<dim3(B_SZ), 1024, 0, stream>>>(lens, P, ms, rep, attn);
}

// Round 5
// 385.016 us; speedup vs baseline: 1.0562x; 1.0338x over previous
//
#include <hip/hip_runtime.h>
#include <hip/hip_bf16.h>
#include <math.h>

// Problem constants (from reference)
#define B_SZ 32
#define T_SZ 4096
#define DV   512   // DIM_VECT
#define DA   256   // DIM_ATTN
#define DK   512   // DIM_ATTN_BID (matrix feature dim)

typedef __attribute__((ext_vector_type(8))) __bf16 bf16x8;
typedef __attribute__((ext_vector_type(4))) __bf16 bf16x4;
typedef __attribute__((ext_vector_type(2))) __bf16 bf16x2;
typedef __attribute__((ext_vector_type(4))) float  f32x4;

// Lengths may arrive as int32 or int64. Valid lengths are in [1, 4096], so for
// int64 little-endian p[1]==0; for int32 p[1] is a real length >= 1.
__device__ inline int get_len(const int* __restrict__ p, int b) {
    return (p[1] == 0) ? p[2 * b] : p[b];
}

// Counted-wait barrier: retire our ds_writes (visible CU-locally), then raw
// s_barrier. Unlike __syncthreads(), does NOT drain vmcnt — prefetched global
// loads stay in flight across the barrier (T4, m218).
#define BAR_LDS()                                             \
    do {                                                      \
        asm volatile("s_waitcnt lgkmcnt(0)" ::: "memory");    \
        __builtin_amdgcn_s_barrier();                         \
    } while (0)

// ---------------------------------------------------------------------------
// Kernel 0 (fused setup): blocks 0..127 convert W_mat f32->bf16;
// blocks 128..383 compute t1[b,a] = vector[b,:]·W_vec[a,:].
// GEMV now uses 256 blocks (b x 8 a-chunks), 8 threads per output with a
// k-split + 3-step shuffle reduce — the old version used 32 blocks with 128
// serial iterations per thread (latency-bound on 12% of the chip).
// ---------------------------------------------------------------------------
__global__ __launch_bounds__(256) void setup_kernel(
    const float* __restrict__ wmat, __bf16* __restrict__ wmat_bf,
    const float* __restrict__ vector, const float* __restrict__ wvec,
    float* __restrict__ t1) {
    int blk = blockIdx.x, tid = threadIdx.x;
    if (blk < 128) {
        int i = (blk * 256 + tid) * 4;
        float4 v = *(const float4*)(wmat + i);
        bf16x4 o;
        o[0] = (__bf16)v.x; o[1] = (__bf16)v.y; o[2] = (__bf16)v.z; o[3] = (__bf16)v.w;
        *(bf16x4*)(wmat_bf + i) = o;
        return;
    }
    int g  = blk - 128;          // 0..255
    int b  = g >> 3;             // batch row
    int a  = (g & 7) * 32 + (tid >> 3);   // output index (32 per block)
    int k0 = (tid & 7) * 64;     // this thread's k-slice (64 floats)
    const float4* w = (const float4*)(wvec + (size_t)a * DV + k0);
    const float4* x = (const float4*)(vector + (size_t)b * DV + k0);
    float acc = 0.f;
#pragma unroll
    for (int k = 0; k < 16; k++) {
        float4 wv = w[k]; float4 xv = x[k];
        acc += wv.x * xv.x + wv.y * xv.y + wv.z * xv.z + wv.w * xv.w;
    }
    // reduce across the 8 k-slice lanes (lanes grouped contiguously, 8 | 64)
    acc += __shfl_xor(acc, 1, 64);
    acc += __shfl_xor(acc, 2, 64);
    acc += __shfl_xor(acc, 4, 64);
    if ((tid & 7) == 0) t1[b * DA + a] = acc;
}

// ---------------------------------------------------------------------------
// Kernel 1: fused logits + block-local online-softmax partials.
// GEMM: A staged f32->bf16 into a PERSISTENT [64][520] bf16 LDS tile.
// Depth-2 register prefetch for the A (HBM) stream; B (L2) at distance 1.
// k-loop barriers are lgkmcnt(0)+raw s_barrier (no vmcnt drain) so prefetched
// global loads stay in flight across k-steps (T4).
// Epilogue: block-local softmax stats + P[d] partial from the LDS tile.
// (Unchanged from round 4 — it sits near its ~21 µs HBM A-read floor.)
// ---------------------------------------------------------------------------
#define TM   64
#define LDA2 520                 // 512 + 8 pad elems: row stride 1040 B ≡ 4 banks, 16B-aligned
#define NBLK (T_SZ / TM)         // 64 t-blocks per batch row

__global__ __launch_bounds__(256) void logits_kernel(
    const float* __restrict__ matrix, const __bf16* __restrict__ wmat,
    const float* __restrict__ t1, const float* __restrict__ wattn,
    const int* __restrict__ lens, float* __restrict__ logits,
    float* __restrict__ P, float* __restrict__ ms) {
    int b  = blockIdx.y;
    int blk = blockIdx.x;
    int t0 = blk * TM;
    int len = get_len(lens, b);
    if (t0 >= len) return;   // inactive blocks: combine kernel never reads their slots

    __shared__ __bf16 sA[TM][LDA2];      // 66.56 KB persistent tile
    __shared__ float s_t1[DA];
    __shared__ float s_wa[DA];
    __shared__ float s_logit[TM];
    __shared__ float sw[TM];

    int tid = threadIdx.x;
    s_t1[tid] = t1[b * DA + tid];
    s_wa[tid] = wattn[tid];
    if (tid < TM) s_logit[tid] = 0.f;

    int wave = tid >> 6, lane = tid & 63;
    int col  = lane & 15;            // t-row (A) / a-col (B) within 16x16 tile
    int koff = (lane >> 4) * 8;      // k sub-offset (bf16 elems)

    // staging assignment: 16 lanes per row, 4 floats (16B) per lane
    int srow = tid >> 4;             // 0..15 (rows srow, srow+16, +32, +48)
    int soff = (tid & 15) * 4;       // k index 0..60

    const float* Abase = matrix + ((size_t)b * T_SZ + t0) * DK;
    const __bf16* Bp[4];
#pragma unroll
    for (int nt = 0; nt < 4; nt++)
        Bp[nt] = wmat + (size_t)(wave * 64 + nt * 16 + col) * DK + koff;

    f32x4 acc[4][4];
    f32x4 zero = {0.f, 0.f, 0.f, 0.f};
#pragma unroll
    for (int i = 0; i < 4; i++)
#pragma unroll
        for (int j = 0; j < 4; j++) acc[i][j] = zero;

    float4 arA[4], arB[4];   // A-slab register pipeline (two named banks)
    uint4  brA[8], brB[8];   // B-slab register pipeline

    // ---- prologue: issue A slab0 (->arA) + slab1 (->arB) and B slab0 (->brA);
    //      convert+write slab0 to LDS cols [0,64)
#pragma unroll
    for (int r = 0; r < 4; r++)
        arA[r] = *(const float4*)(Abase + (size_t)(srow + r * 16) * DK + soff);
#pragma unroll
    for (int r = 0; r < 4; r++)
        arB[r] = *(const float4*)(Abase + (size_t)(srow + r * 16) * DK + 64 + soff);
#pragma unroll
    for (int s = 0; s < 2; s++)
#pragma unroll
        for (int nt = 0; nt < 4; nt++)
            brA[s * 4 + nt] = *(const uint4*)(Bp[nt] + s * 32);

#pragma unroll
    for (int r = 0; r < 4; r++) {
        float4 v = arA[r];
        bf16x4 o;
        o[0] = (__bf16)v.x; o[1] = (__bf16)v.y; o[2] = (__bf16)v.z; o[3] = (__bf16)v.w;
        *(bf16x4*)&sA[srow + r * 16][soff] = o;
    }
    BAR_LDS();   // arB/brA stay in flight into step 0

    // ---- one pipeline step: consume slab ks (LDS + brCUR), issue A ks+2
    //      (->arCUR), issue B ks+1 (->brNXT), write A ks+1 (arNXT) to LDS.
#define K_STEP(ks, arCUR, arNXT, brCUR, brNXT)                                        \
    {                                                                                 \
        const int kb = (ks) * 64;                                                     \
        if ((ks) < 6) {                                                               \
            _Pragma("unroll")                                                         \
            for (int r = 0; r < 4; r++)                                               \
                arCUR[r] = *(const float4*)(Abase + (size_t)(srow + r * 16) * DK      \
                                            + kb + 128 + soff);                       \
        }                                                                             \
        if ((ks) < 7) {                                                               \
            _Pragma("unroll")                                                         \
            for (int s = 0; s < 2; s++)                                               \
                _Pragma("unroll")                                                     \
                for (int nt = 0; nt < 4; nt++)                                        \
                    brNXT[s * 4 + nt] = *(const uint4*)(Bp[nt] + kb + 64 + s * 32);   \
        }                                                                             \
        bf16x8 af[2][4];                                                              \
        _Pragma("unroll")                                                             \
        for (int s = 0; s < 2; s++)                                                   \
            _Pragma("unroll")                                                         \
            for (int mt = 0; mt < 4; mt++)                                            \
                af[s][mt] = *(const bf16x8*)&sA[mt * 16 + col][kb + s * 32 + koff];   \
        _Pragma("unroll")                                                             \
        for (int s = 0; s < 2; s++)                                                   \
            _Pragma("unroll")                                                         \
            for (int mt = 0; mt < 4; mt++)                                            \
                _Pragma("unroll")                                                     \
                for (int nt = 0; nt < 4; nt++)                                        \
                    acc[mt][nt] = __builtin_amdgcn_mfma_f32_16x16x32_bf16(            \
                        af[s][mt], *(bf16x8*)&brCUR[s * 4 + nt], acc[mt][nt], 0, 0, 0); \
        if ((ks) < 7) {                                                               \
            _Pragma("unroll")                                                         \
            for (int r = 0; r < 4; r++) {                                             \
                float4 v = arNXT[r];                                                  \
                bf16x4 o;                                                             \
                o[0] = (__bf16)v.x; o[1] = (__bf16)v.y;                               \
                o[2] = (__bf16)v.z; o[3] = (__bf16)v.w;                               \
                *(bf16x4*)&sA[srow + r * 16][kb + 64 + soff] = o;                     \
            }                                                                         \
        }                                                                             \
        BAR_LDS();                                                                    \
    }

    K_STEP(0, arA, arB, brA, brB)
    K_STEP(1, arB, arA, brB, brA)
    K_STEP(2, arA, arB, brA, brB)
    K_STEP(3, arB, arA, brB, brA)
    K_STEP(4, arA, arB, brA, brB)
    K_STEP(5, arB, arA, brB, brA)
    K_STEP(6, arA, arB, brA, brB)
    K_STEP(7, arB, arA, brB, brA)
#undef K_STEP

    // logits epilogue: v = W_attn[a]*relu(t1[a]+t2), reduce over wave's a-quarter.
    // C/D layout (verified): col = lane&15, row = (lane>>4)*4 + reg
    int rg = lane >> 4;
#pragma unroll
    for (int mt = 0; mt < 4; mt++) {
#pragma unroll
        for (int r = 0; r < 4; r++) {
            float v = 0.f;
#pragma unroll
            for (int nt = 0; nt < 4; nt++) {
                int a = wave * 64 + nt * 16 + col;
                float x = acc[mt][nt][r] + s_t1[a];
                v += s_wa[a] * fmaxf(x, 0.f);
            }
#pragma unroll
            for (int off = 1; off < 16; off <<= 1) v += __shfl_xor(v, off, 64);
            if (col == 0) atomicAdd(&s_logit[mt * 16 + rg * 4 + r], v);
        }
    }
    __syncthreads();

    // block-local online-softmax stats (wave 0 only: lane t holds logit t)
    if (tid < TM) {
        float l = s_logit[tid];
        bool valid = (t0 + tid) < len;
        float m = valid ? l : -1e30f;
#pragma unroll
        for (int off = 32; off; off >>= 1) m = fmaxf(m, __shfl_xor(m, off, 64));
        float w = valid ? __expf(l - m) : 0.f;
        sw[tid] = w;
        float s = w;
#pragma unroll
        for (int off = 32; off; off >>= 1) s += __shfl_xor(s, off, 64);
        if (tid == 0) {
            ms[(b * NBLK + blk) * 2]     = m;
            ms[(b * NBLK + blk) * 2 + 1] = s;
        }
        logits[(size_t)b * T_SZ + t0 + tid] = l;   // raw logit (masked later)
    }
    __syncthreads();

    // partial representation: P[d] = sum_t sw[t] * M[t,d], read from the
    // persistent LDS tile (bf16) — no global re-read. At fixed t the wave
    // reads 256 contiguous bytes (2-way bank alias = free).
    int d = 2 * tid;
    int nv = min(TM, len - t0);
    float p0 = 0.f, p1 = 0.f;
#pragma unroll 4
    for (int t = 0; t < nv; t++) {
        float w = sw[t];
        bf16x2 mv = *(const bf16x2*)&sA[t][d];
        p0 = fmaf(w, (float)mv[0], p0);
        p1 = fmaf(w, (float)mv[1], p1);
    }
    float* Pb = P + ((size_t)(b * NBLK + blk)) * DV;
    Pb[d]     = p0;
    Pb[d + 1] = p1;
}

// ---------------------------------------------------------------------------
// Kernel 2: combine partials (exact flash-style merge) + write rep + normalize
// attention row. Grid (B_SZ, 5) of 256-thread blocks: slice 0 = stats + rep
// (2-way ILP over d); slices 1..4 = attn-row quarters with redundantly
// computed (deterministic) stats. 5x the CU coverage of the old 32-block
// version, which was latency-bound on its serial P-reduction.
// ---------------------------------------------------------------------------
__global__ __launch_bounds__(256) void combine_kernel(
    const int* __restrict__ lens, const float* __restrict__ P,
    const float* __restrict__ ms, float* __restrict__ rep,
    float* __restrict__ attn) {
    int b = blockIdx.x, slice = blockIdx.y, tid = threadIdx.x;
    int len = get_len(lens, b);
    int nblk = (len + TM - 1) / TM;

    __shared__ float sscale[NBLK];  // exp(m_blk - m)
    __shared__ float s_gm, s_gS;

    if (tid < NBLK) {   // NBLK=64 -> exactly wave 0
        float lm = (tid < nblk) ? ms[(b * NBLK + tid) * 2]     : -1e30f;
        float ls = (tid < nblk) ? ms[(b * NBLK + tid) * 2 + 1] : 0.f;
        float m = lm;
#pragma unroll
        for (int off = 32; off; off >>= 1) m = fmaxf(m, __shfl_xor(m, off, 64));
        float sc = (tid < nblk) ? __expf(lm - m) : 0.f;
        float S = sc * ls;
#pragma unroll
        for (int off = 32; off; off >>= 1) S += __shfl_xor(S, off, 64);
        sscale[tid] = sc;
        if (tid == 0) { s_gm = m; s_gS = S; }
    }
    __syncthreads();
    float m = s_gm;
    float invS = 1.f / s_gS;

    if (slice == 0) {
        // rep[b,d] = invS * sum_blk sscale[blk] * P[b,blk,d]; 2 d per thread
        float acc0 = 0.f, acc1 = 0.f;
        const float* Pb0 = P + (size_t)b * NBLK * DV + tid;
        const float* Pb1 = Pb0 + 256;
        for (int blk = 0; blk < nblk; blk++) {
            float sc = sscale[blk];
            acc0 = fmaf(sc, Pb0[(size_t)blk * DV], acc0);
            acc1 = fmaf(sc, Pb1[(size_t)blk * DV], acc1);
        }
        rep[b * DV + tid]       = acc0 * invS;
        rep[b * DV + tid + 256] = acc1 * invS;
    } else {
        // normalize one 1024-element quarter of the attention row
        int tbase = (slice - 1) * 1024;
        float* row = attn + (size_t)b * T_SZ + tbase;
#pragma unroll
        for (int i = 0; i < 4; i++) {
            int t = tid + i * 256;
            float l = row[t];
            row[t] = (tbase + t < len) ? __expf(l - m) * invS : 0.f;
        }
    }
}

// ---------------------------------------------------------------------------
extern "C" void kernel_launch(void* const* d_in, const int* in_sizes, int n_in,
                              void* d_out, int out_size, void* d_ws, size_t ws_size,
                              hipStream_t stream) {
    const float* vector = (const float*)d_in[0];
    const float* matrix = (const float*)d_in[1];
    const int*   lens   = (const int*)d_in[2];
    const float* wvec   = (const float*)d_in[3];
    const float* wmat   = (const float*)d_in[4];
    const float* wattn  = (const float*)d_in[5];

    float* rep  = (float*)d_out;            // [32, 512]
    float* attn = rep + B_SZ * DV;          // [32, 4096] raw logits -> normalized

    char* ws = (char*)d_ws;
    float*  t1      = (float*)ws;                        // 32 KB
    __bf16* wmat_bf = (__bf16*)(ws + 32768);             // 256 KB
    float*  P       = (float*)(ws + 32768 + 262144);     // 32*64*512 f32 = 4 MB
    float*  ms      = (float*)(ws + 32768 + 262144 + 4194304);  // 32*64*2 f32 = 16 KB

    setup_kernel<<<dim3(384), 256, 0, stream>>>(wmat, wmat_bf, vector, wvec, t1);
    logits_kernel<<<dim3(NBLK, B_SZ), 256, 0, stream>>>(matrix, wmat_bf, t1, wattn,
                                                        lens, attn, P, ms);
    combine_kernel<<<dim3(B_SZ, 5), 256, 0, stream>>>(lens, P, ms, rep, attn);
}